// Round 17
// baseline (55.611 us; speedup 1.0000x reference)
//
#include <hip/hip_runtime.h>
#include <hip/hip_bf16.h>
#include <math.h>

#define NROWS 4096
#define DIM   256
#define HALF_MASK 2047
#define BLOCK 256

typedef __attribute__((ext_vector_type(8))) short bf16x8;
typedef __attribute__((ext_vector_type(4))) float f32x4;

// order-preserving float -> uint transform (fallback path only)
__device__ __forceinline__ unsigned fkey(float f) {
    unsigned u = __float_as_uint(f);
    return (u & 0x80000000u) ? ~u : (u | 0x80000000u);
}

// 16-bit linear quantized distance key: q = clamp((1-dot)*16384).
// Monotone in distance; quantum 6.1e-5 in dot (same order as the bf16-S
// quantization already proven harmless). Linear quantization spreads the
// top byte over ~128 bins -> plain LDS atomics stay ~2-way (free).
__device__ __forceinline__ unsigned qkey16(float dot) {
    const float f = fmaf(dot, -16384.f, 16384.f);
    return (unsigned)fminf(fmaxf(f, 0.f), 65535.f);
}

__device__ __forceinline__ float bf16f(unsigned short b) {
    return __uint_as_float(((unsigned)b) << 16);
}

// ===========================================================================
// FAST PATH: prep -> bf16 MFMA Gram (bf16 S, coalesced stores) ->
//            rowsel 2-rows/block 2-pass (partials, no atomics) -> reduce
// ===========================================================================

__global__ void prep_bf16_kernel(const float* __restrict__ feat,
                                 const int* __restrict__ labels,
                                 short* __restrict__ fnb,
                                 float* __restrict__ sq,
                                 unsigned char* __restrict__ lab8)
{
    const int row  = blockIdx.x * 4 + (threadIdx.x >> 6);
    const int lane = threadIdx.x & 63;
    float4 x = ((const float4*)feat)[(size_t)row * 64 + lane];
    float ss = x.x*x.x + x.y*x.y + x.z*x.z + x.w*x.w;
    #pragma unroll
    for (int m = 1; m < 64; m <<= 1) ss += __shfl_xor(ss, m, 64);
    const float nrm = sqrtf(ss);
    float4 f; f.x = x.x/nrm; f.y = x.y/nrm; f.z = x.z/nrm; f.w = x.w/nrm;

    union { __hip_bfloat16 b; unsigned short s; } cv[4];
    cv[0].b = __float2bfloat16(f.x); cv[1].b = __float2bfloat16(f.y);
    cv[2].b = __float2bfloat16(f.z); cv[3].b = __float2bfloat16(f.w);
    ushort4 h; h.x = cv[0].s; h.y = cv[1].s; h.z = cv[2].s; h.w = cv[3].s;
    ((ushort4*)fnb)[(size_t)row * 64 + lane] = h;

    float s2 = f.x*f.x + f.y*f.y + f.z*f.z + f.w*f.w;
    #pragma unroll
    for (int m = 1; m < 64; m <<= 1) s2 += __shfl_xor(s2, m, 64);
    if (lane == 0) {
        sq[row]   = s2;                       // used by fallback path only
        lab8[row] = (unsigned char)labels[row & HALF_MASK];
    }
}

// Gram: S = fn * fn^T (4096x4096, K=256), bf16 MFMA 16x16x32, bf16 out.
// Reg-staged LDS loads (R15, measured best); coalesced dwordx4 C-store via
// LDS restage. blockIdx XCD-swizzled (bijective: 1024 % 8 == 0).
__global__ __launch_bounds__(256) void gram_kernel(
        const short* __restrict__ fnb, unsigned short* __restrict__ Sb)
{
    __shared__ __align__(16) short smem[128 * 128];   // As | Bs, then C tile
    short* As = smem;                                 // 128*64
    short* Bs = smem + 128 * 64;                      // 128*64

    const int tid  = threadIdx.x;
    const int lane = tid & 63;
    const int wv   = tid >> 6;
    const int wm   = wv >> 1, wn = wv & 1;
    const int wgid = (blockIdx.x & 7) * 128 + (blockIdx.x >> 3);   // XCD swizzle
    const int bi   = wgid >> 5;
    const int bj   = wgid & 31;
    const int i0   = bi * 128, j0 = bj * 128;

    f32x4 acc[4][4];
    const f32x4 zero = {0.f, 0.f, 0.f, 0.f};
    #pragma unroll
    for (int a = 0; a < 4; ++a)
        #pragma unroll
        for (int b = 0; b < 4; ++b) acc[a][b] = zero;

    const int srow   = tid >> 3;
    const int schunk = tid & 7;

    for (int kt = 0; kt < 4; ++kt) {
        #pragma unroll
        for (int is = 0; is < 4; ++is) {
            const int row = is * 32 + srow;
            const size_t gsrc = (size_t)kt * 64 + schunk * 8;
            uint4 va = *(const uint4*)(fnb + (size_t)(i0 + row) * DIM + gsrc);
            uint4 vb = *(const uint4*)(fnb + (size_t)(j0 + row) * DIM + gsrc);
            const int dst = row * 64 + ((schunk ^ (row & 7)) * 8);
            *(uint4*)(As + dst) = va;
            *(uint4*)(Bs + dst) = vb;
        }
        __syncthreads();
        #pragma unroll
        for (int kk = 0; kk < 2; ++kk) {
            bf16x8 af[4], bfr[4];
            #pragma unroll
            for (int mi = 0; mi < 4; ++mi) {
                const int row = wm * 64 + mi * 16 + (lane & 15);
                const int ch  = kk * 4 + (lane >> 4);
                af[mi] = *(const bf16x8*)(As + row * 64 + ((ch ^ (row & 7)) * 8));
            }
            #pragma unroll
            for (int ni = 0; ni < 4; ++ni) {
                const int row = wn * 64 + ni * 16 + (lane & 15);
                const int ch  = kk * 4 + (lane >> 4);
                bfr[ni] = *(const bf16x8*)(Bs + row * 64 + ((ch ^ (row & 7)) * 8));
            }
            #pragma unroll
            for (int mi = 0; mi < 4; ++mi)
                #pragma unroll
                for (int ni = 0; ni < 4; ++ni)
                    acc[mi][ni] = __builtin_amdgcn_mfma_f32_16x16x32_bf16(
                        af[mi], bfr[ni], acc[mi][ni], 0, 0, 0);
        }
        __syncthreads();
    }
    // all waves past final barrier: As/Bs dead, reuse smem for the C tile

    const int cq = lane >> 4;
    const int cc = lane & 15;
    #pragma unroll
    for (int mi = 0; mi < 4; ++mi) {
        #pragma unroll
        for (int ni = 0; ni < 4; ++ni) {
            const int cl = wn * 64 + ni * 16 + cc;
            const int rb = wm * 64 + mi * 16 + cq * 4;
            #pragma unroll
            for (int v = 0; v < 4; ++v) {
                union { __hip_bfloat16 b; unsigned short s; } cv;
                cv.b = __float2bfloat16(acc[mi][ni][v]);
                const int r = rb + v;
                smem[r * 128 + (cl ^ (((unsigned)r & 7u) << 3))] = (short)cv.s;
            }
        }
    }
    __syncthreads();

    #pragma unroll
    for (int i = 0; i < 8; ++i) {
        const int chunk = i * 256 + tid;
        const int r     = chunk >> 4;
        const int g     = (chunk & 15) ^ ((unsigned)r & 7u);
        const uint4 val = *(const uint4*)(smem + r * 128 + g * 8);
        *(uint4*)(Sb + (size_t)(i0 + r) * NROWS + j0 + ((chunk & 15) * 8)) = val;
    }
}

// suffix-scan a 256-bin histogram within one wave, pick threshold digit
__device__ __forceinline__ void radix_scan(const unsigned* hb, int lane,
                                           unsigned& P, unsigned& K, int shift) {
    const uint4 h = ((const uint4*)hb)[lane];
    const unsigned s3 = h.w;
    const unsigned s2 = h.z + s3;
    const unsigned s1 = h.y + s2;
    const unsigned s0 = h.x + s1;
    unsigned x = s0;
    #pragma unroll
    for (int d = 1; d < 64; d <<= 1) {
        const unsigned y = __shfl_down(x, d, 64);
        if (lane + d < 64) x += y;
    }
    const unsigned E = x - s0;                    // sum over lanes > lane
    unsigned pk = 0u;
    const unsigned Sv0 = E + s0, Sv1 = E + s1, Sv2 = E + s2, Sv3 = E + s3;
    if (Sv0 >= K && Sv0 - h.x < K) pk = ((unsigned)(lane*4+0) << 16) | (K - (Sv0 - h.x));
    if (Sv1 >= K && Sv1 - h.y < K) pk = ((unsigned)(lane*4+1) << 16) | (K - (Sv1 - h.y));
    if (Sv2 >= K && Sv2 - h.z < K) pk = ((unsigned)(lane*4+2) << 16) | (K - (Sv2 - h.z));
    if (Sv3 >= K && Sv3 - h.w < K) pk = ((unsigned)(lane*4+3) << 16) | (K - (Sv3 - h.w));
    #pragma unroll
    for (int m = 1; m < 64; m <<= 1) pk |= __shfl_xor(pk, m, 64);
    P |= (pk >> 16) << shift;
    K  = pk & 0xFFFFu;
}

// TWO rows per 256-thread block (2048 blocks): labels loaded once, both
// rows' radix phases share the same barriers -> 5 barriers / 2 rows
// (was 5/row). Scans are wave-local (each wave scans both hists, no sync).
// Keys packed qA | qB<<16. Output: partial[row] (plain store, no atomics).
__global__ __launch_bounds__(256) void rowsel_b2_kernel(
        const unsigned short* __restrict__ Sb,
        const unsigned char* __restrict__ lab8,
        float* __restrict__ partial)
{
    __shared__ unsigned hist[2][2][256];   // [pass][row][bin], pre-zeroed
    __shared__ float    zb[2][4];
    __shared__ unsigned tieb[2][4];
    __shared__ float    sdb[2][4];
    __shared__ int      cntb[2][4];

    const int tid  = threadIdx.x;
    const int lane = tid & 63;
    const int w    = tid >> 6;
    const int rA   = blockIdx.x * 2;
    const int rB   = rA + 1;

    // ---- issue all loads first (latency hides under zero + key build) ----
    const uint4* SA = (const uint4*)(Sb + (size_t)rA * NROWS);
    const uint4* SB = (const uint4*)(Sb + (size_t)rB * NROWS);
    const uint4 a0 = SA[tid * 2], a1 = SA[tid * 2 + 1];
    const uint4 b0 = SB[tid * 2], b1 = SB[tid * 2 + 1];
    const uint4 lv = ((const uint4*)lab8)[tid];

    // zero all 4 histograms: 1024 words = 256 threads x uint4
    ((uint4*)&hist[0][0][0])[tid] = make_uint4(0u, 0u, 0u, 0u);
    __syncthreads();                                   // B0

    const unsigned swA[8] = {a0.x, a0.y, a0.z, a0.w, a1.x, a1.y, a1.z, a1.w};
    const unsigned swB[8] = {b0.x, b0.y, b0.z, b0.w, b1.x, b1.y, b1.z, b1.w};
    const unsigned lw[4]  = {lv.x, lv.y, lv.z, lv.w};

    // keys (packed) + Z + fused pass-0 histograms
    unsigned qp[16];
    float zA = 0.f, zB = 0.f;
    const int j0 = tid * 16;
    #pragma unroll
    for (int e = 0; e < 16; ++e) {
        const unsigned wa = swA[e >> 1], wb = swB[e >> 1];
        const float dA = bf16f((unsigned short)((e & 1) ? (wa >> 16) : (wa & 0xFFFFu)));
        const float dB = bf16f((unsigned short)((e & 1) ? (wb >> 16) : (wb & 0xFFFFu)));
        const unsigned qA = qkey16(dA);
        const unsigned qB = qkey16(dB);
        qp[e] = qA | (qB << 16);
        zA += (j0 + e == rA) ? 0.f : __expf(10.f * dA);
        zB += (j0 + e == rB) ? 0.f : __expf(10.f * dB);
        atomicAdd(&hist[0][0][qA >> 8], 1u);
        atomicAdd(&hist[0][1][qB >> 8], 1u);
    }
    #pragma unroll
    for (int m = 1; m < 64; m <<= 1) {
        zA += __shfl_xor(zA, m, 64);
        zB += __shfl_xor(zB, m, 64);
    }
    if (lane == 0) { zb[0][w] = zA; zb[1][w] = zB; }
    __syncthreads();                                   // B1

    unsigned PA = 0u, KA = 128u, PB = 0u, KB = 128u;
    radix_scan(hist[0][0], lane, PA, KA, 8);
    radix_scan(hist[0][1], lane, PB, KB, 8);

    // ---- pass 1 (low byte) into pass-1 hists (pre-zeroed) ----
    #pragma unroll
    for (int e = 0; e < 16; ++e) {
        const unsigned qA = qp[e] & 0xFFFFu;
        const unsigned qB = qp[e] >> 16;
        if ((qA >> 8) == (PA >> 8)) atomicAdd(&hist[1][0][qA & 255u], 1u);
        if ((qB >> 8) == (PB >> 8)) atomicAdd(&hist[1][1][qB & 255u], 1u);
    }
    __syncthreads();                                   // B2
    radix_scan(hist[1][0], lane, PA, KA, 0);           // PA = full 16-bit key
    radix_scan(hist[1][1], lane, PB, KB, 0);

    // ---- tie ranks (tid-major == ascending j) ----
    int tcA = 0, tcB = 0;
    #pragma unroll
    for (int e = 0; e < 16; ++e) {
        tcA += ((qp[e] & 0xFFFFu) == PA) ? 1 : 0;
        tcB += ((qp[e] >> 16) == PB) ? 1 : 0;
    }
    int pA = tcA, pB = tcB;
    #pragma unroll
    for (int d = 1; d < 64; d <<= 1) {
        const int oA = __shfl_up(pA, d, 64);
        const int oB = __shfl_up(pB, d, 64);
        if (lane >= d) { pA += oA; pB += oB; }
    }
    if (lane == 63) { tieb[0][w] = (unsigned)pA; tieb[1][w] = (unsigned)pB; }
    __syncthreads();                                   // B3
    int tA = pA - tcA, tB = pB - tcB;
    #pragma unroll
    for (int ww = 0; ww < 4; ++ww) if (ww < w) {
        tA += (int)tieb[0][ww];
        tB += (int)tieb[1][ww];
    }

    // ---- accumulate over selected & same-class & j != row ----
    const unsigned myA = lab8[rA], myB = lab8[rB];
    float sdA = 0.f, sdB = 0.f; int cnA = 0, cnB = 0;
    #pragma unroll
    for (int e = 0; e < 16; ++e) {
        const unsigned lj = (lw[e >> 2] >> ((e & 3) * 8)) & 255u;
        const unsigned qA = qp[e] & 0xFFFFu;
        const unsigned qB = qp[e] >> 16;
        bool selA = (qA > PA);
        if (qA == PA) { selA = (tA < (int)KA); ++tA; }
        bool selB = (qB > PB);
        if (qB == PB) { selB = (tB < (int)KB); ++tB; }
        if (selA && (j0 + e != rA) && lj == myA) {
            ++cnA;
            const unsigned wa = swA[e >> 1];
            sdA += bf16f((unsigned short)((e & 1) ? (wa >> 16) : (wa & 0xFFFFu)));
        }
        if (selB && (j0 + e != rB) && lj == myB) {
            ++cnB;
            const unsigned wb = swB[e >> 1];
            sdB += bf16f((unsigned short)((e & 1) ? (wb >> 16) : (wb & 0xFFFFu)));
        }
    }
    #pragma unroll
    for (int m = 1; m < 64; m <<= 1) {
        sdA += __shfl_xor(sdA, m, 64);
        sdB += __shfl_xor(sdB, m, 64);
        cnA += __shfl_xor(cnA, m, 64);
        cnB += __shfl_xor(cnB, m, 64);
    }
    if (lane == 0) {
        sdb[0][w] = sdA; cntb[0][w] = cnA;
        sdb[1][w] = sdB; cntb[1][w] = cnB;
    }
    __syncthreads();                                   // B4

    if (tid < 2) {
        const int c = cntb[tid][0] + cntb[tid][1] + cntb[tid][2] + cntb[tid][3];
        float r = 0.f;
        if (c > 0) {
            const float s = sdb[tid][0] + sdb[tid][1] + sdb[tid][2] + sdb[tid][3];
            const float Z = zb[tid][0] + zb[tid][1] + zb[tid][2] + zb[tid][3];
            const float mlpp = (10.f * s) / (float)c - __logf(Z);
            r = -(0.1f / 0.07f) * mlpp * (1.f / (float)NROWS);
        }
        partial[rA + tid] = r;                         // plain store
    }
}

// final reduction: one block sums the 4096 partials, writes out[0]
__global__ __launch_bounds__(256) void reduce_kernel(
        const float* __restrict__ partial, float* __restrict__ out)
{
    __shared__ float wsum[4];
    const int tid  = threadIdx.x;
    const int lane = tid & 63;
    const int w    = tid >> 6;
    float s = 0.f;
    #pragma unroll
    for (int k = 0; k < 4; ++k) {
        const float4 v = ((const float4*)partial)[tid + 256 * k];
        s += v.x + v.y + v.z + v.w;
    }
    #pragma unroll
    for (int m = 1; m < 64; m <<= 1) s += __shfl_xor(s, m, 64);
    if (lane == 0) wsum[w] = s;
    __syncthreads();
    if (tid == 0) out[0] = wsum[0] + wsum[1] + wsum[2] + wsum[3];
}

// ===========================================================================
// FALLBACK PATH (small d_ws): R2 fused kernels (verified correct)
// ===========================================================================

__global__ void prep_kernel(const float* __restrict__ feat,
                            const int* __restrict__ labels,
                            float* __restrict__ fn,
                            float* __restrict__ sq,
                            unsigned char* __restrict__ lab8,
                            float* __restrict__ out)
{
    const int row  = blockIdx.x * 4 + (threadIdx.x >> 6);
    const int lane = threadIdx.x & 63;
    float4 x = ((const float4*)feat)[(size_t)row * 64 + lane];
    float ss = x.x*x.x + x.y*x.y + x.z*x.z + x.w*x.w;
    #pragma unroll
    for (int m = 1; m < 64; m <<= 1) ss += __shfl_xor(ss, m, 64);
    const float nrm = sqrtf(ss);
    float4 f; f.x = x.x/nrm; f.y = x.y/nrm; f.z = x.z/nrm; f.w = x.w/nrm;
    ((float4*)fn)[(size_t)row * 64 + lane] = f;
    float s2 = f.x*f.x + f.y*f.y + f.z*f.z + f.w*f.w;
    #pragma unroll
    for (int m = 1; m < 64; m <<= 1) s2 += __shfl_xor(s2, m, 64);
    if (lane == 0) {
        sq[row]  = s2;
        lab8[row] = (unsigned char)labels[row & HALF_MASK];
    }
    if (blockIdx.x == 0 && threadIdx.x == 0) out[0] = 0.0f;
}

#define R 4
__global__ __launch_bounds__(BLOCK, 3) void rowloss_kernel(
        const float* __restrict__ fn,
        const float* __restrict__ sq,
        const unsigned char* __restrict__ lab8,
        float* __restrict__ out)
{
    __shared__ __align__(16) float fi[R][DIM];
    __shared__ unsigned hist[R * 256];
    __shared__ float    wz[R][4];
    __shared__ unsigned wsc[R][4];
    __shared__ unsigned selT[R], selK[R];
    __shared__ float    wsd[R][4];
    __shared__ int      wcnt[R][4];

    const int tid  = threadIdx.x;
    const int lane = tid & 63;
    const int wv   = tid >> 6;
    const int i0   = blockIdx.x * R;
    const int j0   = tid * 16;

    for (int idx = tid; idx < R * DIM; idx += BLOCK)
        fi[idx >> 8][idx & 255] = fn[(size_t)i0 * DIM + idx];
    __syncthreads();

    const float4* fn4 = (const float4*)fn;
    const float4* fi4 = (const float4*)&fi[0][0];

    float acc[16][R];
    #pragma unroll
    for (int jj = 0; jj < 16; ++jj)
        #pragma unroll
        for (int r = 0; r < R; ++r) acc[jj][r] = 0.0f;

    for (int c = 0; c < 32; ++c) {
        float fir[R][8];
        #pragma unroll
        for (int r = 0; r < R; ++r) {
            float4 a = fi4[r * 64 + c * 2];
            float4 b = fi4[r * 64 + c * 2 + 1];
            fir[r][0] = a.x; fir[r][1] = a.y; fir[r][2] = a.z; fir[r][3] = a.w;
            fir[r][4] = b.x; fir[r][5] = b.y; fir[r][6] = b.z; fir[r][7] = b.w;
        }
        #pragma unroll
        for (int jj = 0; jj < 16; ++jj) {
            const float4* pp = fn4 + (size_t)(j0 + jj) * 64 + c * 2;
            float4 x = pp[0];
            float4 y = pp[1];
            #pragma unroll
            for (int r = 0; r < R; ++r) {
                float s = acc[jj][r];
                s = fmaf(x.x, fir[r][0], s); s = fmaf(x.y, fir[r][1], s);
                s = fmaf(x.z, fir[r][2], s); s = fmaf(x.w, fir[r][3], s);
                s = fmaf(y.x, fir[r][4], s); s = fmaf(y.y, fir[r][5], s);
                s = fmaf(y.z, fir[r][6], s); s = fmaf(y.w, fir[r][7], s);
                acc[jj][r] = s;
            }
        }
    }

    float sqr[16];
    #pragma unroll
    for (int k = 0; k < 16; ++k) sqr[k] = sq[j0 + k];

    float lzr[R];
    {
        float zloc[R];
        #pragma unroll
        for (int r = 0; r < R; ++r) {
            const int ir = i0 + r;
            float z = 0.0f;
            #pragma unroll
            for (int k = 0; k < 16; ++k) {
                float e = __expf(10.0f * acc[k][r]);
                z += (j0 + k == ir) ? 0.0f : e;
            }
            zloc[r] = z;
        }
        #pragma unroll
        for (int r = 0; r < R; ++r) {
            float z = zloc[r];
            #pragma unroll
            for (int m = 1; m < 64; m <<= 1) z += __shfl_xor(z, m, 64);
            if (lane == 0) wz[r][wv] = z;
        }
        __syncthreads();
        #pragma unroll
        for (int r = 0; r < R; ++r)
            lzr[r] = __logf(wz[r][0] + wz[r][1] + wz[r][2] + wz[r][3]);
    }

    unsigned Pr[R] = {0, 0, 0, 0};
    unsigned Kr[R] = {128u, 128u, 128u, 128u};
    #pragma unroll
    for (int pass = 0; pass < 4; ++pass) {
        const int shift = 24 - 8 * pass;
        #pragma unroll
        for (int r = 0; r < R; ++r) hist[r * 256 + tid] = 0u;
        __syncthreads();
        #pragma unroll
        for (int r = 0; r < R; ++r) {
            #pragma unroll
            for (int k = 0; k < 16; ++k) {
                unsigned uu = fkey(fmaf(-2.0f, acc[k][r], sqr[k]));
                bool act = (pass == 0) ||
                    (((unsigned long long)(uu ^ Pr[r]) >> (shift + 8)) == 0ull);
                if (act) atomicAdd(&hist[r * 256 + ((uu >> shift) & 255u)], 1u);
            }
        }
        __syncthreads();
        unsigned g[R], Pv[R];
        #pragma unroll
        for (int r = 0; r < R; ++r) { g[r] = hist[r * 256 + (255 - tid)]; Pv[r] = g[r]; }
        #pragma unroll
        for (int dd = 1; dd < 64; dd <<= 1) {
            #pragma unroll
            for (int r = 0; r < R; ++r) {
                unsigned o = __shfl_up(Pv[r], dd, 64);
                if (lane >= dd) Pv[r] += o;
            }
        }
        if (lane == 63) {
            #pragma unroll
            for (int r = 0; r < R; ++r) wsc[r][wv] = Pv[r];
        }
        __syncthreads();
        #pragma unroll
        for (int r = 0; r < R; ++r) {
            unsigned off = 0;
            #pragma unroll
            for (int ww = 0; ww < 4; ++ww) if (ww < wv) off += wsc[r][ww];
            const unsigned Sv = Pv[r] + off;
            const unsigned Sn = Sv - g[r];
            if (Sv >= Kr[r] && Sn < Kr[r]) {
                selT[r] = Pr[r] | ((unsigned)(255 - tid) << shift);
                selK[r] = Kr[r] - Sn;
            }
        }
        __syncthreads();
        #pragma unroll
        for (int r = 0; r < R; ++r) { Pr[r] = selT[r]; Kr[r] = selK[r]; }
        __syncthreads();
    }

    int tb[R];
    {
        int tcr[R], Pt[R];
        #pragma unroll
        for (int r = 0; r < R; ++r) {
            int c = 0;
            #pragma unroll
            for (int k = 0; k < 16; ++k)
                if (fkey(fmaf(-2.0f, acc[k][r], sqr[k])) == Pr[r]) c++;
            tcr[r] = c; Pt[r] = c;
        }
        #pragma unroll
        for (int dd = 1; dd < 64; dd <<= 1) {
            #pragma unroll
            for (int r = 0; r < R; ++r) {
                int o = __shfl_up(Pt[r], dd, 64);
                if (lane >= dd) Pt[r] += o;
            }
        }
        if (lane == 63) {
            #pragma unroll
            for (int r = 0; r < R; ++r) wsc[r][wv] = (unsigned)Pt[r];
        }
        __syncthreads();
        #pragma unroll
        for (int r = 0; r < R; ++r) {
            int off = 0;
            #pragma unroll
            for (int ww = 0; ww < 4; ++ww) if (ww < wv) off += (int)wsc[r][ww];
            tb[r] = Pt[r] + off - tcr[r];
        }
    }

    const uint4 labv = ((const uint4*)lab8)[tid];
    const unsigned labw[4] = {labv.x, labv.y, labv.z, labv.w};

    #pragma unroll
    for (int r = 0; r < R; ++r) {
        const int ir = i0 + r;
        const unsigned my = lab8[ir];
        float sd = 0.0f; int cnt = 0; int t = tb[r];
        #pragma unroll
        for (int k = 0; k < 16; ++k) {
            const unsigned uu = fkey(fmaf(-2.0f, acc[k][r], sqr[k]));
            bool sel = (uu > Pr[r]);
            if (uu == Pr[r]) { sel = (t < (int)Kr[r]); t++; }
            const unsigned lj = (labw[k >> 2] >> ((k & 3) * 8)) & 255u;
            if (sel && (j0 + k != ir) && lj == my) { cnt++; sd += acc[k][r]; }
        }
        #pragma unroll
        for (int m = 1; m < 64; m <<= 1) {
            sd  += __shfl_xor(sd, m, 64);
            cnt += __shfl_xor(cnt, m, 64);
        }
        if (lane == 0) { wsd[r][wv] = sd; wcnt[r][wv] = cnt; }
    }
    __syncthreads();

    if (tid < R) {
        const int r = tid;
        const int c = wcnt[r][0] + wcnt[r][1] + wcnt[r][2] + wcnt[r][3];
        if (c > 0) {
            const float sd = wsd[r][0] + wsd[r][1] + wsd[r][2] + wsd[r][3];
            const float mlpp = (10.0f * sd) / (float)c - lzr[r];
            atomicAdd(out, -(0.1f / 0.07f) * mlpp * (1.0f / (float)NROWS));
        }
    }
}

// ===========================================================================

extern "C" void kernel_launch(void* const* d_in, const int* in_sizes, int n_in,
                              void* d_out, int out_size, void* d_ws, size_t ws_size,
                              hipStream_t stream) {
    (void)in_sizes; (void)n_in; (void)out_size;
    const float* feat  = (const float*)d_in[0];
    const int* labels  = (const int*)d_in[1];
    float* out = (float*)d_out;

    // fast-path workspace layout (S stored as bf16: 32 MB)
    const size_t offS = 0;                                   // 4096*4096 bf16
    const size_t offF = (size_t)NROWS * NROWS * 2;           // fn bf16
    const size_t offQ = offF + (size_t)NROWS * DIM * 2;      // sq f32
    const size_t offL = offQ + (size_t)NROWS * 4;            // labels u8
    const size_t offP = offL + (size_t)NROWS;                // partials f32
    const size_t need = offP + (size_t)NROWS * 4;

    if (ws_size >= need) {
        unsigned short* Sb = (unsigned short*)((char*)d_ws + offS);
        short* fnb = (short*)((char*)d_ws + offF);
        float* sq  = (float*)((char*)d_ws + offQ);
        unsigned char* lab8 = (unsigned char*)((char*)d_ws + offL);
        float* partial = (float*)((char*)d_ws + offP);

        prep_bf16_kernel<<<NROWS / 4, BLOCK, 0, stream>>>(feat, labels, fnb, sq, lab8);
        gram_kernel<<<(NROWS / 128) * (NROWS / 128), BLOCK, 0, stream>>>(fnb, Sb);
        rowsel_b2_kernel<<<NROWS / 2, BLOCK, 0, stream>>>(Sb, lab8, partial);
        reduce_kernel<<<1, BLOCK, 0, stream>>>(partial, out);
    } else {
        float* fn = (float*)d_ws;
        float* sq = fn + (size_t)NROWS * DIM;
        unsigned char* lab8 = (unsigned char*)(sq + NROWS);

        prep_kernel<<<NROWS / 4, BLOCK, 0, stream>>>(feat, labels, fn, sq, lab8, out);
        rowloss_kernel<<<NROWS / R, BLOCK, 0, stream>>>(fn, sq, lab8, out);
    }
}

// Round 18
// 53.825 us; speedup vs baseline: 1.0332x; 1.0332x over previous
//
#include <hip/hip_runtime.h>
#include <hip/hip_bf16.h>
#include <math.h>

#define NROWS 4096
#define DIM   256
#define HALF_MASK 2047
#define BLOCK 256

typedef __attribute__((ext_vector_type(8))) short bf16x8;
typedef __attribute__((ext_vector_type(4))) float f32x4;

// order-preserving float -> uint transform (fallback path only)
__device__ __forceinline__ unsigned fkey(float f) {
    unsigned u = __float_as_uint(f);
    return (u & 0x80000000u) ? ~u : (u | 0x80000000u);
}

// 16-bit linear quantized distance key: q = clamp((1-dot)*16384).
// Monotone in distance; quantum 6.1e-5 in dot. Linear quantization spreads
// the top byte over ~128 bins -> plain LDS atomics stay ~2-way (free).
__device__ __forceinline__ unsigned qkey16(float dot) {
    const float f = fmaf(dot, -16384.f, 16384.f);
    return (unsigned)fminf(fmaxf(f, 0.f), 65535.f);
}

__device__ __forceinline__ float bf16f(unsigned short b) {
    return __uint_as_float(((unsigned)b) << 16);
}

// ===========================================================================
// FAST PATH (R15 configuration -- best measured, 53.86us):
// prep -> bf16 MFMA Gram (reg-staged, coalesced C-store) ->
// rowsel 1-row/block 2-pass (partials, no atomics) -> reduce
// ===========================================================================

__global__ void prep_bf16_kernel(const float* __restrict__ feat,
                                 const int* __restrict__ labels,
                                 short* __restrict__ fnb,
                                 float* __restrict__ sq,
                                 unsigned char* __restrict__ lab8)
{
    const int row  = blockIdx.x * 4 + (threadIdx.x >> 6);
    const int lane = threadIdx.x & 63;
    float4 x = ((const float4*)feat)[(size_t)row * 64 + lane];
    float ss = x.x*x.x + x.y*x.y + x.z*x.z + x.w*x.w;
    #pragma unroll
    for (int m = 1; m < 64; m <<= 1) ss += __shfl_xor(ss, m, 64);
    const float nrm = sqrtf(ss);
    float4 f; f.x = x.x/nrm; f.y = x.y/nrm; f.z = x.z/nrm; f.w = x.w/nrm;

    union { __hip_bfloat16 b; unsigned short s; } cv[4];
    cv[0].b = __float2bfloat16(f.x); cv[1].b = __float2bfloat16(f.y);
    cv[2].b = __float2bfloat16(f.z); cv[3].b = __float2bfloat16(f.w);
    ushort4 h; h.x = cv[0].s; h.y = cv[1].s; h.z = cv[2].s; h.w = cv[3].s;
    ((ushort4*)fnb)[(size_t)row * 64 + lane] = h;

    float s2 = f.x*f.x + f.y*f.y + f.z*f.z + f.w*f.w;
    #pragma unroll
    for (int m = 1; m < 64; m <<= 1) s2 += __shfl_xor(s2, m, 64);
    if (lane == 0) {
        sq[row]   = s2;                       // used by fallback path only
        lab8[row] = (unsigned char)labels[row & HALF_MASK];
    }
}

// Gram: S = fn * fn^T (4096x4096, K=256), bf16 MFMA 16x16x32, bf16 out.
// Reg-staged LDS loads; coalesced dwordx4 C-store via LDS restage.
// blockIdx XCD-swizzled (bijective: 1024 % 8 == 0).
__global__ __launch_bounds__(256) void gram_kernel(
        const short* __restrict__ fnb, unsigned short* __restrict__ Sb)
{
    __shared__ __align__(16) short smem[128 * 128];   // As | Bs, then C tile
    short* As = smem;                                 // 128*64
    short* Bs = smem + 128 * 64;                      // 128*64

    const int tid  = threadIdx.x;
    const int lane = tid & 63;
    const int wv   = tid >> 6;
    const int wm   = wv >> 1, wn = wv & 1;
    const int wgid = (blockIdx.x & 7) * 128 + (blockIdx.x >> 3);   // XCD swizzle
    const int bi   = wgid >> 5;
    const int bj   = wgid & 31;
    const int i0   = bi * 128, j0 = bj * 128;

    f32x4 acc[4][4];
    const f32x4 zero = {0.f, 0.f, 0.f, 0.f};
    #pragma unroll
    for (int a = 0; a < 4; ++a)
        #pragma unroll
        for (int b = 0; b < 4; ++b) acc[a][b] = zero;

    const int srow   = tid >> 3;
    const int schunk = tid & 7;

    for (int kt = 0; kt < 4; ++kt) {
        #pragma unroll
        for (int is = 0; is < 4; ++is) {
            const int row = is * 32 + srow;
            const size_t gsrc = (size_t)kt * 64 + schunk * 8;
            uint4 va = *(const uint4*)(fnb + (size_t)(i0 + row) * DIM + gsrc);
            uint4 vb = *(const uint4*)(fnb + (size_t)(j0 + row) * DIM + gsrc);
            const int dst = row * 64 + ((schunk ^ (row & 7)) * 8);
            *(uint4*)(As + dst) = va;
            *(uint4*)(Bs + dst) = vb;
        }
        __syncthreads();
        #pragma unroll
        for (int kk = 0; kk < 2; ++kk) {
            bf16x8 af[4], bfr[4];
            #pragma unroll
            for (int mi = 0; mi < 4; ++mi) {
                const int row = wm * 64 + mi * 16 + (lane & 15);
                const int ch  = kk * 4 + (lane >> 4);
                af[mi] = *(const bf16x8*)(As + row * 64 + ((ch ^ (row & 7)) * 8));
            }
            #pragma unroll
            for (int ni = 0; ni < 4; ++ni) {
                const int row = wn * 64 + ni * 16 + (lane & 15);
                const int ch  = kk * 4 + (lane >> 4);
                bfr[ni] = *(const bf16x8*)(Bs + row * 64 + ((ch ^ (row & 7)) * 8));
            }
            #pragma unroll
            for (int mi = 0; mi < 4; ++mi)
                #pragma unroll
                for (int ni = 0; ni < 4; ++ni)
                    acc[mi][ni] = __builtin_amdgcn_mfma_f32_16x16x32_bf16(
                        af[mi], bfr[ni], acc[mi][ni], 0, 0, 0);
        }
        __syncthreads();
    }
    // all waves past final barrier: As/Bs dead, reuse smem for the C tile

    // stage C tile (bf16) into LDS; 8-short-group XOR swizzle by row
    const int cq = lane >> 4;
    const int cc = lane & 15;
    #pragma unroll
    for (int mi = 0; mi < 4; ++mi) {
        #pragma unroll
        for (int ni = 0; ni < 4; ++ni) {
            const int cl = wn * 64 + ni * 16 + cc;
            const int rb = wm * 64 + mi * 16 + cq * 4;
            #pragma unroll
            for (int v = 0; v < 4; ++v) {
                union { __hip_bfloat16 b; unsigned short s; } cv;
                cv.b = __float2bfloat16(acc[mi][ni][v]);
                const int r = rb + v;
                smem[r * 128 + (cl ^ (((unsigned)r & 7u) << 3))] = (short)cv.s;
            }
        }
    }
    __syncthreads();

    // coalesced store: 2048 x 16B chunks, 16 per row
    #pragma unroll
    for (int i = 0; i < 8; ++i) {
        const int chunk = i * 256 + tid;
        const int r     = chunk >> 4;
        const int g     = (chunk & 15) ^ ((unsigned)r & 7u);   // swizzled group
        const uint4 val = *(const uint4*)(smem + r * 128 + g * 8);
        *(uint4*)(Sb + (size_t)(i0 + r) * NROWS + j0 + ((chunk & 15) * 8)) = val;
    }
}

// suffix-scan a 256-bin histogram within one wave, pick threshold digit
__device__ __forceinline__ void radix_scan(const unsigned* hb, int lane,
                                           unsigned& P, unsigned& K, int shift) {
    const uint4 h = ((const uint4*)hb)[lane];
    const unsigned s3 = h.w;
    const unsigned s2 = h.z + s3;
    const unsigned s1 = h.y + s2;
    const unsigned s0 = h.x + s1;
    unsigned x = s0;
    #pragma unroll
    for (int d = 1; d < 64; d <<= 1) {
        const unsigned y = __shfl_down(x, d, 64);
        if (lane + d < 64) x += y;
    }
    const unsigned E = x - s0;                    // sum over lanes > lane
    unsigned pk = 0u;
    const unsigned Sv0 = E + s0, Sv1 = E + s1, Sv2 = E + s2, Sv3 = E + s3;
    if (Sv0 >= K && Sv0 - h.x < K) pk = ((unsigned)(lane*4+0) << 16) | (K - (Sv0 - h.x));
    if (Sv1 >= K && Sv1 - h.y < K) pk = ((unsigned)(lane*4+1) << 16) | (K - (Sv1 - h.y));
    if (Sv2 >= K && Sv2 - h.z < K) pk = ((unsigned)(lane*4+2) << 16) | (K - (Sv2 - h.z));
    if (Sv3 >= K && Sv3 - h.w < K) pk = ((unsigned)(lane*4+3) << 16) | (K - (Sv3 - h.w));
    #pragma unroll
    for (int m = 1; m < 64; m <<= 1) pk |= __shfl_xor(pk, m, 64);
    P |= (pk >> 16) << shift;
    K  = pk & 0xFFFFu;
}

// one row per 256-thread block; 16-bit quantized key -> TWO radix passes,
// 5 barriers. Output: partial[row] (plain store, no atomics).
__global__ __launch_bounds__(256) void rowsel_b_kernel(
        const unsigned short* __restrict__ Sb,
        const unsigned char* __restrict__ lab8,
        float* __restrict__ partial)
{
    __shared__ unsigned hist[2][256];
    __shared__ float    zb[4];
    __shared__ unsigned tieb[4];
    __shared__ float    sdb[4];
    __shared__ int      cntb[4];

    const int tid  = threadIdx.x;
    const int lane = tid & 63;
    const int w    = tid >> 6;
    const int row  = blockIdx.x;

    hist[0][tid] = 0u;
    hist[1][tid] = 0u;
    __syncthreads();                                   // B0

    // ---- load 16 bf16 dots (2 x uint4) + 16 labels (1 x uint4) ----
    const uint4 s0 = ((const uint4*)(Sb + (size_t)row * NROWS))[tid * 2];
    const uint4 s1 = ((const uint4*)(Sb + (size_t)row * NROWS))[tid * 2 + 1];
    const uint4 lv = ((const uint4*)lab8)[tid];
    unsigned sw[8] = {s0.x, s0.y, s0.z, s0.w, s1.x, s1.y, s1.z, s1.w};
    const unsigned lw[4] = {lv.x, lv.y, lv.z, lv.w};

    // keys + Z + fused pass-0 histogram (key top byte)
    unsigned q[16];
    float z = 0.f;
    const int j0 = tid * 16;
    #pragma unroll
    for (int e = 0; e < 16; ++e) {
        const unsigned word = sw[e >> 1];
        const float dot = bf16f((unsigned short)((e & 1) ? (word >> 16) : (word & 0xFFFFu)));
        q[e] = qkey16(dot);
        z += (j0 + e == row) ? 0.f : __expf(10.f * dot);
        atomicAdd(&hist[0][q[e] >> 8], 1u);
    }
    #pragma unroll
    for (int m = 1; m < 64; m <<= 1) z += __shfl_xor(z, m, 64);
    if (lane == 0) zb[w] = z;
    __syncthreads();                                   // B1

    unsigned P = 0u, K = 128u;
    radix_scan(hist[0], lane, P, K, 8);

    // ---- pass 1 (low byte) into hist[1] (pre-zeroed) ----
    #pragma unroll
    for (int e = 0; e < 16; ++e)
        if ((q[e] >> 8) == (P >> 8))
            atomicAdd(&hist[1][q[e] & 255u], 1u);
    __syncthreads();                                   // B2
    radix_scan(hist[1], lane, P, K, 0);                // P = full 16-bit key

    // ---- tie ranks (tid-major == ascending j) ----
    int tcnt = 0;
    #pragma unroll
    for (int e = 0; e < 16; ++e) tcnt += (q[e] == P) ? 1 : 0;
    int p = tcnt;
    #pragma unroll
    for (int d = 1; d < 64; d <<= 1) {
        const int o = __shfl_up(p, d, 64);
        if (lane >= d) p += o;
    }
    if (lane == 63) tieb[w] = (unsigned)p;
    __syncthreads();                                   // B3
    int t = p - tcnt;
    #pragma unroll
    for (int ww = 0; ww < 4; ++ww) if (ww < w) t += (int)tieb[ww];

    // ---- accumulate over selected & same-class & j != row ----
    const unsigned my = lab8[row];
    float sd = 0.f; int cnt = 0;
    #pragma unroll
    for (int e = 0; e < 16; ++e) {
        bool sel = (q[e] > P);
        if (q[e] == P) { sel = (t < (int)K); ++t; }
        const unsigned lj = (lw[e >> 2] >> ((e & 3) * 8)) & 255u;
        if (sel && (j0 + e != row) && lj == my) {
            ++cnt;
            const unsigned word = sw[e >> 1];
            sd += bf16f((unsigned short)((e & 1) ? (word >> 16) : (word & 0xFFFFu)));
        }
    }
    #pragma unroll
    for (int m = 1; m < 64; m <<= 1) {
        sd  += __shfl_xor(sd, m, 64);
        cnt += __shfl_xor(cnt, m, 64);
    }
    if (lane == 0) { sdb[w] = sd; cntb[w] = cnt; }
    __syncthreads();                                   // B4

    if (tid == 0) {
        const int c = cntb[0] + cntb[1] + cntb[2] + cntb[3];
        float r = 0.f;
        if (c > 0) {
            const float s = sdb[0] + sdb[1] + sdb[2] + sdb[3];
            const float Z = zb[0] + zb[1] + zb[2] + zb[3];
            const float mlpp = (10.f * s) / (float)c - __logf(Z);
            r = -(0.1f / 0.07f) * mlpp * (1.f / (float)NROWS);
        }
        partial[row] = r;                              // plain store
    }
}

// final reduction: one block sums the 4096 partials, writes out[0]
__global__ __launch_bounds__(256) void reduce_kernel(
        const float* __restrict__ partial, float* __restrict__ out)
{
    __shared__ float wsum[4];
    const int tid  = threadIdx.x;
    const int lane = tid & 63;
    const int w    = tid >> 6;
    float s = 0.f;
    #pragma unroll
    for (int k = 0; k < 4; ++k) {
        const float4 v = ((const float4*)partial)[tid + 256 * k];
        s += v.x + v.y + v.z + v.w;
    }
    #pragma unroll
    for (int m = 1; m < 64; m <<= 1) s += __shfl_xor(s, m, 64);
    if (lane == 0) wsum[w] = s;
    __syncthreads();
    if (tid == 0) out[0] = wsum[0] + wsum[1] + wsum[2] + wsum[3];
}

// ===========================================================================
// FALLBACK PATH (small d_ws): R2 fused kernels (verified correct)
// ===========================================================================

__global__ void prep_kernel(const float* __restrict__ feat,
                            const int* __restrict__ labels,
                            float* __restrict__ fn,
                            float* __restrict__ sq,
                            unsigned char* __restrict__ lab8,
                            float* __restrict__ out)
{
    const int row  = blockIdx.x * 4 + (threadIdx.x >> 6);
    const int lane = threadIdx.x & 63;
    float4 x = ((const float4*)feat)[(size_t)row * 64 + lane];
    float ss = x.x*x.x + x.y*x.y + x.z*x.z + x.w*x.w;
    #pragma unroll
    for (int m = 1; m < 64; m <<= 1) ss += __shfl_xor(ss, m, 64);
    const float nrm = sqrtf(ss);
    float4 f; f.x = x.x/nrm; f.y = x.y/nrm; f.z = x.z/nrm; f.w = x.w/nrm;
    ((float4*)fn)[(size_t)row * 64 + lane] = f;
    float s2 = f.x*f.x + f.y*f.y + f.z*f.z + f.w*f.w;
    #pragma unroll
    for (int m = 1; m < 64; m <<= 1) s2 += __shfl_xor(s2, m, 64);
    if (lane == 0) {
        sq[row]  = s2;
        lab8[row] = (unsigned char)labels[row & HALF_MASK];
    }
    if (blockIdx.x == 0 && threadIdx.x == 0) out[0] = 0.0f;
}

#define R 4
__global__ __launch_bounds__(BLOCK, 3) void rowloss_kernel(
        const float* __restrict__ fn,
        const float* __restrict__ sq,
        const unsigned char* __restrict__ lab8,
        float* __restrict__ out)
{
    __shared__ __align__(16) float fi[R][DIM];
    __shared__ unsigned hist[R * 256];
    __shared__ float    wz[R][4];
    __shared__ unsigned wsc[R][4];
    __shared__ unsigned selT[R], selK[R];
    __shared__ float    wsd[R][4];
    __shared__ int      wcnt[R][4];

    const int tid  = threadIdx.x;
    const int lane = tid & 63;
    const int wv   = tid >> 6;
    const int i0   = blockIdx.x * R;
    const int j0   = tid * 16;

    for (int idx = tid; idx < R * DIM; idx += BLOCK)
        fi[idx >> 8][idx & 255] = fn[(size_t)i0 * DIM + idx];
    __syncthreads();

    const float4* fn4 = (const float4*)fn;
    const float4* fi4 = (const float4*)&fi[0][0];

    float acc[16][R];
    #pragma unroll
    for (int jj = 0; jj < 16; ++jj)
        #pragma unroll
        for (int r = 0; r < R; ++r) acc[jj][r] = 0.0f;

    for (int c = 0; c < 32; ++c) {
        float fir[R][8];
        #pragma unroll
        for (int r = 0; r < R; ++r) {
            float4 a = fi4[r * 64 + c * 2];
            float4 b = fi4[r * 64 + c * 2 + 1];
            fir[r][0] = a.x; fir[r][1] = a.y; fir[r][2] = a.z; fir[r][3] = a.w;
            fir[r][4] = b.x; fir[r][5] = b.y; fir[r][6] = b.z; fir[r][7] = b.w;
        }
        #pragma unroll
        for (int jj = 0; jj < 16; ++jj) {
            const float4* pp = fn4 + (size_t)(j0 + jj) * 64 + c * 2;
            float4 x = pp[0];
            float4 y = pp[1];
            #pragma unroll
            for (int r = 0; r < R; ++r) {
                float s = acc[jj][r];
                s = fmaf(x.x, fir[r][0], s); s = fmaf(x.y, fir[r][1], s);
                s = fmaf(x.z, fir[r][2], s); s = fmaf(x.w, fir[r][3], s);
                s = fmaf(y.x, fir[r][4], s); s = fmaf(y.y, fir[r][5], s);
                s = fmaf(y.z, fir[r][6], s); s = fmaf(y.w, fir[r][7], s);
                acc[jj][r] = s;
            }
        }
    }

    float sqr[16];
    #pragma unroll
    for (int k = 0; k < 16; ++k) sqr[k] = sq[j0 + k];

    float lzr[R];
    {
        float zloc[R];
        #pragma unroll
        for (int r = 0; r < R; ++r) {
            const int ir = i0 + r;
            float z = 0.0f;
            #pragma unroll
            for (int k = 0; k < 16; ++k) {
                float e = __expf(10.0f * acc[k][r]);
                z += (j0 + k == ir) ? 0.0f : e;
            }
            zloc[r] = z;
        }
        #pragma unroll
        for (int r = 0; r < R; ++r) {
            float z = zloc[r];
            #pragma unroll
            for (int m = 1; m < 64; m <<= 1) z += __shfl_xor(z, m, 64);
            if (lane == 0) wz[r][wv] = z;
        }
        __syncthreads();
        #pragma unroll
        for (int r = 0; r < R; ++r)
            lzr[r] = __logf(wz[r][0] + wz[r][1] + wz[r][2] + wz[r][3]);
    }

    unsigned Pr[R] = {0, 0, 0, 0};
    unsigned Kr[R] = {128u, 128u, 128u, 128u};
    #pragma unroll
    for (int pass = 0; pass < 4; ++pass) {
        const int shift = 24 - 8 * pass;
        #pragma unroll
        for (int r = 0; r < R; ++r) hist[r * 256 + tid] = 0u;
        __syncthreads();
        #pragma unroll
        for (int r = 0; r < R; ++r) {
            #pragma unroll
            for (int k = 0; k < 16; ++k) {
                unsigned uu = fkey(fmaf(-2.0f, acc[k][r], sqr[k]));
                bool act = (pass == 0) ||
                    (((unsigned long long)(uu ^ Pr[r]) >> (shift + 8)) == 0ull);
                if (act) atomicAdd(&hist[r * 256 + ((uu >> shift) & 255u)], 1u);
            }
        }
        __syncthreads();
        unsigned g[R], Pv[R];
        #pragma unroll
        for (int r = 0; r < R; ++r) { g[r] = hist[r * 256 + (255 - tid)]; Pv[r] = g[r]; }
        #pragma unroll
        for (int dd = 1; dd < 64; dd <<= 1) {
            #pragma unroll
            for (int r = 0; r < R; ++r) {
                unsigned o = __shfl_up(Pv[r], dd, 64);
                if (lane >= dd) Pv[r] += o;
            }
        }
        if (lane == 63) {
            #pragma unroll
            for (int r = 0; r < R; ++r) wsc[r][wv] = Pv[r];
        }
        __syncthreads();
        #pragma unroll
        for (int r = 0; r < R; ++r) {
            unsigned off = 0;
            #pragma unroll
            for (int ww = 0; ww < 4; ++ww) if (ww < wv) off += wsc[r][ww];
            const unsigned Sv = Pv[r] + off;
            const unsigned Sn = Sv - g[r];
            if (Sv >= Kr[r] && Sn < Kr[r]) {
                selT[r] = Pr[r] | ((unsigned)(255 - tid) << shift);
                selK[r] = Kr[r] - Sn;
            }
        }
        __syncthreads();
        #pragma unroll
        for (int r = 0; r < R; ++r) { Pr[r] = selT[r]; Kr[r] = selK[r]; }
        __syncthreads();
    }

    int tb[R];
    {
        int tcr[R], Pt[R];
        #pragma unroll
        for (int r = 0; r < R; ++r) {
            int c = 0;
            #pragma unroll
            for (int k = 0; k < 16; ++k)
                if (fkey(fmaf(-2.0f, acc[k][r], sqr[k])) == Pr[r]) c++;
            tcr[r] = c; Pt[r] = c;
        }
        #pragma unroll
        for (int dd = 1; dd < 64; dd <<= 1) {
            #pragma unroll
            for (int r = 0; r < R; ++r) {
                int o = __shfl_up(Pt[r], dd, 64);
                if (lane >= dd) Pt[r] += o;
            }
        }
        if (lane == 63) {
            #pragma unroll
            for (int r = 0; r < R; ++r) wsc[r][wv] = (unsigned)Pt[r];
        }
        __syncthreads();
        #pragma unroll
        for (int r = 0; r < R; ++r) {
            int off = 0;
            #pragma unroll
            for (int ww = 0; ww < 4; ++ww) if (ww < wv) off += (int)wsc[r][ww];
            tb[r] = Pt[r] + off - tcr[r];
        }
    }

    const uint4 labv = ((const uint4*)lab8)[tid];
    const unsigned labw[4] = {labv.x, labv.y, labv.z, labv.w};

    #pragma unroll
    for (int r = 0; r < R; ++r) {
        const int ir = i0 + r;
        const unsigned my = lab8[ir];
        float sd = 0.0f; int cnt = 0; int t = tb[r];
        #pragma unroll
        for (int k = 0; k < 16; ++k) {
            const unsigned uu = fkey(fmaf(-2.0f, acc[k][r], sqr[k]));
            bool sel = (uu > Pr[r]);
            if (uu == Pr[r]) { sel = (t < (int)Kr[r]); t++; }
            const unsigned lj = (labw[k >> 2] >> ((k & 3) * 8)) & 255u;
            if (sel && (j0 + k != ir) && lj == my) { cnt++; sd += acc[k][r]; }
        }
        #pragma unroll
        for (int m = 1; m < 64; m <<= 1) {
            sd  += __shfl_xor(sd, m, 64);
            cnt += __shfl_xor(cnt, m, 64);
        }
        if (lane == 0) { wsd[r][wv] = sd; wcnt[r][wv] = cnt; }
    }
    __syncthreads();

    if (tid < R) {
        const int r = tid;
        const int c = wcnt[r][0] + wcnt[r][1] + wcnt[r][2] + wcnt[r][3];
        if (c > 0) {
            const float sd = wsd[r][0] + wsd[r][1] + wsd[r][2] + wsd[r][3];
            const float mlpp = (10.0f * sd) / (float)c - lzr[r];
            atomicAdd(out, -(0.1f / 0.07f) * mlpp * (1.0f / (float)NROWS));
        }
    }
}

// ===========================================================================

extern "C" void kernel_launch(void* const* d_in, const int* in_sizes, int n_in,
                              void* d_out, int out_size, void* d_ws, size_t ws_size,
                              hipStream_t stream) {
    (void)in_sizes; (void)n_in; (void)out_size;
    const float* feat  = (const float*)d_in[0];
    const int* labels  = (const int*)d_in[1];
    float* out = (float*)d_out;

    // fast-path workspace layout (S stored as bf16: 32 MB)
    const size_t offS = 0;                                   // 4096*4096 bf16
    const size_t offF = (size_t)NROWS * NROWS * 2;           // fn bf16
    const size_t offQ = offF + (size_t)NROWS * DIM * 2;      // sq f32
    const size_t offL = offQ + (size_t)NROWS * 4;            // labels u8
    const size_t offP = offL + (size_t)NROWS;                // partials f32
    const size_t need = offP + (size_t)NROWS * 4;

    if (ws_size >= need) {
        unsigned short* Sb = (unsigned short*)((char*)d_ws + offS);
        short* fnb = (short*)((char*)d_ws + offF);
        float* sq  = (float*)((char*)d_ws + offQ);
        unsigned char* lab8 = (unsigned char*)((char*)d_ws + offL);
        float* partial = (float*)((char*)d_ws + offP);

        prep_bf16_kernel<<<NROWS / 4, BLOCK, 0, stream>>>(feat, labels, fnb, sq, lab8);
        gram_kernel<<<(NROWS / 128) * (NROWS / 128), BLOCK, 0, stream>>>(fnb, Sb);
        rowsel_b_kernel<<<NROWS, BLOCK, 0, stream>>>(Sb, lab8, partial);
        reduce_kernel<<<1, BLOCK, 0, stream>>>(partial, out);
    } else {
        float* fn = (float*)d_ws;
        float* sq = fn + (size_t)NROWS * DIM;
        unsigned char* lab8 = (unsigned char*)(sq + NROWS);

        prep_kernel<<<NROWS / 4, BLOCK, 0, stream>>>(feat, labels, fn, sq, lab8, out);
        rowloss_kernel<<<NROWS / R, BLOCK, 0, stream>>>(fn, sq, lab8, out);
    }
}